// Round 10
// baseline (1045.342 us; speedup 1.0000x reference)
//
#include <hip/hip_runtime.h>
#include <hip/hip_cooperative_groups.h>
#include <math.h>

namespace cg = cooperative_groups;

// GATNet_MLP R25: fuse the 6-dispatch build chain (prep, count_hist,
// scan_block, scan_add2, fill, aec) into ONE cooperative kernel with
// grid.sync() between phases. R24 accounting: dispatch work ~310-330us vs
// 429 total -> ~100us in launch boundaries/tails over 14 dispatches.
// 5 boundaries -> 5 grid.sync (cheaper). Grid 1024x256 (4 blk/CU, safe
// co-residency). Compute pipeline (GEMM/sum8/gat_agg/final) unchanged
// from R24 (session-best structure).

#define N_NODES 50000
#define N_EDGES 400000
#define N_GRAPH 64
#define DIN     128
#define NHC     256
#define DOUT    32

typedef _Float16 f16x8 __attribute__((ext_vector_type(8)));
typedef _Float16 f16x4 __attribute__((ext_vector_type(4)));
typedef float    f32x4 __attribute__((ext_vector_type(4)));

#define LDP2 72   // padded LDS row stride in halfs for BK=64 (144B)

// v_fma_mix_f32: acc = pj * (float)half(w, lo/hi) + acc
__device__ __forceinline__ void fma_mix_lo(float& acc, float pj, int w) {
    asm volatile("v_fma_mix_f32 %0, %1, %2, %0 op_sel:[0,0,0] op_sel_hi:[0,1,0]"
                 : "+v"(acc) : "v"(pj), "v"(w));
}
__device__ __forceinline__ void fma_mix_hi(float& acc, float pj, int w) {
    asm volatile("v_fma_mix_f32 %0, %1, %2, %0 op_sel:[0,1,0] op_sel_hi:[0,1,0]"
                 : "+v"(acc) : "v"(pj), "v"(w));
}

// ================= fp16 MFMA GEMM, 128x64 tile, BK=64, pipelined ==========
// mode 0: C fp16 [nrow][256]; if asl!=null also a_s/a_d per-wave 32-col
//   dot-partials -> asb/adb[row*8 + headw] (disjoint plain stores).
// mode 3: NO C write; v=gelu(v+bias); per-graph pooled sums (batch sorted).
__global__ __launch_bounds__(256) void mfma_gemm_kernel(
    const _Float16* __restrict__ Ah, const _Float16* __restrict__ Bh,
    const float* __restrict__ bias, _Float16* __restrict__ Ch,
    const float* __restrict__ asl, const float* __restrict__ adl,
    float* __restrict__ asb, float* __restrict__ adb,
    const int* __restrict__ batch, float* __restrict__ pooled,
    int nrow, int K, int mode)
{
    __shared__ __align__(16) _Float16 sAh[128][LDP2];   // 18.4 KB
    __shared__ __align__(16) _Float16 sBh[64][LDP2];    //  9.2 KB

    const int tid = threadIdx.x, lane = tid & 63, wid = tid >> 6;
    const int wm = wid & 1, wn = wid >> 1;

    int xt, yt;
    if (gridDim.x == 4) {
        int bid = blockIdx.x + (blockIdx.y << 2);
        yt = (bid >> 5) * 8 + (bid & 7);
        xt = (bid >> 3) & 3;
    } else { xt = blockIdx.x; yt = blockIdx.y; }
    const int row0 = yt * 128, col0 = xt * 64;
    if (row0 >= nrow) return;

    const int frow = lane & 15, fk = (lane >> 4) * 8;

    f32x4 acc[4][2] = {};
    f16x8 pA[4], pB[2];

    // prefetch k-tile 0
#pragma unroll
    for (int p = 0; p < 4; p++) {
        int idx = tid + p * 256;                     // 0..1023
        int r = idx >> 3, ch = (idx & 7) * 8;
        int gr = row0 + r;
        pA[p] = (gr < nrow) ? *(const f16x8*)(Ah + (long)gr * K + ch) : (f16x8)0;
    }
#pragma unroll
    for (int p = 0; p < 2; p++) {
        int idx = tid + p * 256;                     // 0..511
        int r = idx >> 3, ch = (idx & 7) * 8;
        pB[p] = *(const f16x8*)(Bh + (long)(col0 + r) * K + ch);
    }

    for (int k0 = 0; k0 < K; k0 += 64) {
#pragma unroll
        for (int p = 0; p < 4; p++) {
            int idx = tid + p * 256;
            *(f16x8*)&sAh[idx >> 3][(idx & 7) * 8] = pA[p];
        }
#pragma unroll
        for (int p = 0; p < 2; p++) {
            int idx = tid + p * 256;
            *(f16x8*)&sBh[idx >> 3][(idx & 7) * 8] = pB[p];
        }
        __syncthreads();

        if (k0 + 64 < K) {
            int kn = k0 + 64;
#pragma unroll
            for (int p = 0; p < 4; p++) {
                int idx = tid + p * 256;
                int r = idx >> 3, ch = (idx & 7) * 8;
                int gr = row0 + r;
                pA[p] = (gr < nrow) ? *(const f16x8*)(Ah + (long)gr * K + kn + ch) : (f16x8)0;
            }
#pragma unroll
            for (int p = 0; p < 2; p++) {
                int idx = tid + p * 256;
                int r = idx >> 3, ch = (idx & 7) * 8;
                pB[p] = *(const f16x8*)(Bh + (long)(col0 + r) * K + kn + ch);
            }
        }

#pragma unroll
        for (int sub = 0; sub < 2; sub++) {
            const int fks = fk + sub * 32;
            f16x8 bh[2];
#pragma unroll
            for (int nt = 0; nt < 2; nt++)
                bh[nt] = *(const f16x8*)&sBh[wn * 32 + nt * 16 + frow][fks];
#pragma unroll
            for (int mt = 0; mt < 4; mt++) {
                f16x8 ah = *(const f16x8*)&sAh[wm * 64 + mt * 16 + frow][fks];
#pragma unroll
                for (int nt = 0; nt < 2; nt++)
                    acc[mt][nt] = __builtin_amdgcn_mfma_f32_16x16x32_f16(ah, bh[nt], acc[mt][nt], 0, 0, 0);
            }
        }
        __syncthreads();
    }

    const int crow0 = row0 + wm * 64 + (lane >> 4) * 4;
    const int ccol0 = col0 + wn * 32 + (lane & 15);

    if (mode == 0) {
#pragma unroll
        for (int mt = 0; mt < 4; mt++)
#pragma unroll
            for (int nt = 0; nt < 2; nt++) {
                int col = ccol0 + nt * 16;
#pragma unroll
                for (int r = 0; r < 4; r++) {
                    int row = crow0 + mt * 16 + r;
                    if (row < nrow) Ch[(long)row * 256 + col] = (_Float16)acc[mt][nt][r];
                }
            }
        // fused a_s/a_d dot-partials from fp32 acc regs: plain disjoint stores.
        if (asl != nullptr) {
            const float asl0 = asl[ccol0], asl1 = asl[ccol0 + 16];
            const float adl0 = adl[ccol0], adl1 = adl[ccol0 + 16];
            const int headw = (col0 + wn * 32) >> 5;
#pragma unroll
            for (int mt = 0; mt < 4; mt++) {
#pragma unroll
                for (int r = 0; r < 4; r++) {
                    float s = acc[mt][0][r] * asl0 + acc[mt][1][r] * asl1;
                    float d = acc[mt][0][r] * adl0 + acc[mt][1][r] * adl1;
                    s += __shfl_xor(s, 1); s += __shfl_xor(s, 2);
                    s += __shfl_xor(s, 4); s += __shfl_xor(s, 8);
                    d += __shfl_xor(d, 1); d += __shfl_xor(d, 2);
                    d += __shfl_xor(d, 4); d += __shfl_xor(d, 8);
                    if ((lane & 15) == 0) {
                        int row = crow0 + mt * 16 + r;
                        if (row < nrow) {
                            asb[row * 8 + headw] = s;
                            adb[row * 8 + headw] = d;
                        }
                    }
                }
            }
        }
    } else {
        // mode 3: gelu(v+bias) -> per-graph pooled sums, register pre-accum (R11).
        float* pool = (float*)&sAh[0][0];            // 16*64 floats = 4KB
        const int g0 = batch[row0];
        const int rlast = (row0 + 127 < nrow) ? row0 + 127 : nrow - 1;
        const int gspan = batch[rlast] - g0 + 1;
        const bool fits = (gspan <= 16);
        for (int i = tid; i < 16 * 64; i += 256) pool[i] = 0.f;
        __syncthreads();

        const float b0 = bias[ccol0], b1 = bias[ccol0 + 16];
        const int lc0 = ccol0 - col0, lc1 = lc0 + 16;
        float sum0 = 0.f, sum1 = 0.f;
        int curg = -1;
#pragma unroll
        for (int mt = 0; mt < 4; mt++) {
#pragma unroll
            for (int r = 0; r < 4; r++) {
                int row = crow0 + mt * 16 + r;
                if (row >= nrow) continue;
                int g = batch[row];
                if (g != curg) {
                    if (curg >= 0) {
                        if (fits) {
                            atomicAdd(&pool[(curg - g0) * 64 + lc0], sum0);
                            atomicAdd(&pool[(curg - g0) * 64 + lc1], sum1);
                        } else {
                            atomicAdd(&pooled[curg * 256 + ccol0], sum0);
                            atomicAdd(&pooled[curg * 256 + ccol0 + 16], sum1);
                        }
                    }
                    curg = g; sum0 = 0.f; sum1 = 0.f;
                }
                float v0 = acc[mt][0][r] + b0;
                float v1 = acc[mt][1][r] + b1;
                sum0 += 0.5f * v0 * (1.f + erff(v0 * 0.7071067811865475f));
                sum1 += 0.5f * v1 * (1.f + erff(v1 * 0.7071067811865475f));
            }
        }
        if (curg >= 0) {
            if (fits) {
                atomicAdd(&pool[(curg - g0) * 64 + lc0], sum0);
                atomicAdd(&pool[(curg - g0) * 64 + lc1], sum1);
            } else {
                atomicAdd(&pooled[curg * 256 + ccol0], sum0);
                atomicAdd(&pooled[curg * 256 + ccol0 + 16], sum1);
            }
        }
        __syncthreads();
        if (fits) {
            for (int i = tid; i < gspan * 64; i += 256) {
                float val = pool[i];
                if (val != 0.f)
                    atomicAdd(&pooled[(g0 + (i >> 6)) * 256 + col0 + (i & 63)], val);
            }
        }
    }
}

// -------- sum8: reduce 8 per-wave partials -> slot 0, in place (layer 3) ----
__global__ __launch_bounds__(256) void sum8_kernel(
    float* __restrict__ asb3, float* __restrict__ adb3, int n)
{
    int r = blockIdx.x * 256 + threadIdx.x;
    if (r >= n) return;
    const float4* a = (const float4*)(asb3 + (long)r * 8);
    float4 a0 = a[0], a1 = a[1];
    asb3[(long)r * 8] = a0.x + a0.y + a0.z + a0.w + a1.x + a1.y + a1.z + a1.w;
    const float4* b = (const float4*)(adb3 + (long)r * 8);
    float4 b0 = b[0], b1 = b[1];
    adb3[(long)r * 8] = b0.x + b0.y + b0.z + b0.w + b1.x + b1.y + b1.z + b1.w;
}

// ================= cooperative build kernel =================
// P0 prep jobs -> P1 count_hist -> P2 scan_block -> P3 scan_add2 ->
// P4 fill -> P5 aec, with grid.sync() between phases.
#define J0 1600000                       // x convert (float4 units): N*DIN/4
#define J1 32768                         // W1 transpose (256 x 128)
#define J2 65536                         // W2
#define J3 65536                         // W3
#define J4 65536                         // fcW1
#define J5 16384                         // zero pooled (64*256)
#define J6 N_NODES                       // zero deg
#define J7 64                            // zero gcnt
#define J9 85                            // me_all jobs (40+40+5)
#define JTOT (J0+J1+J2+J3+J4+J5+J6+J7+J9)
#define NBC  ((N_NODES + 255) / 256)     // 196 scan chunks

struct BuildArgs {
    const float* x;
    const float* W1; const float* W2; const float* W3; const float* F1;
    const float* We1; const float* ae1;
    const float* We2; const float* ae2;
    const float* We3; const float* ae3;
    const int* ei; const int* batch; const float* ea;
    _Float16* xh;
    _Float16* W1th; _Float16* W2th; _Float16* W3th; _Float16* F1th;
    float* pooled; int* deg; int* gcnt; float* MeAll;
    int* rowstart; int* cursor; int* partial;
    int2* csr2; int* csr; _Float16* aec;
};

__device__ __forceinline__ void t_one(const float* W, _Float16* Bh,
                                      long id, int K, int realN)
{
    long n = id / K, k = id - n * K;
    Bh[id] = (_Float16)W[k * realN + n];
}

__device__ __forceinline__ void prep_job(const BuildArgs& a, long idx)
{
    if (idx < J0) {
        float4 v = ((const float4*)a.x)[idx];
        f16x4 h;
        h[0] = (_Float16)v.x; h[1] = (_Float16)v.y;
        h[2] = (_Float16)v.z; h[3] = (_Float16)v.w;
        *(f16x4*)(a.xh + idx * 4) = h;
        return;
    }
    idx -= J0;
    if (idx < J1) { t_one(a.W1, a.W1th, idx, DIN, NHC); return; }
    idx -= J1;
    if (idx < J2) { t_one(a.W2, a.W2th, idx, NHC, NHC); return; }
    idx -= J2;
    if (idx < J3) { t_one(a.W3, a.W3th, idx, NHC, NHC); return; }
    idx -= J3;
    if (idx < J4) { t_one(a.F1, a.F1th, idx, NHC, NHC); return; }
    idx -= J4;
    if (idx < J5) { a.pooled[idx] = 0.f; return; }
    idx -= J5;
    if (idx < J6) { a.deg[idx] = 0; return; }
    idx -= J6;
    if (idx < J7) { a.gcnt[idx] = 0; return; }
    idx -= J7;
    if (idx < J9) {
        int l, j, hh, H, C;
        int id = (int)idx;
        if (id < 40)      { l = 0; H = 8; C = 32;  j = id >> 3; hh = id & 7; }
        else if (id < 80) { l = 1; H = 8; C = 32;  int r = id - 40; j = r >> 3; hh = r & 7; }
        else              { l = 2; H = 1; C = 256; j = id - 80; hh = 0; }
        const float* We = (l == 0) ? a.We1 : (l == 1) ? a.We2 : a.We3;
        const float* ae = (l == 0) ? a.ae1 : (l == 1) ? a.ae2 : a.ae3;
        float s = 0.f;
        for (int c = 0; c < C; c++) s += We[j * NHC + hh * C + c] * ae[hh * C + c];
        a.MeAll[l * 40 + j * H + hh] = s;
        return;
    }
}

__global__ __launch_bounds__(256) void build_kernel(BuildArgs a)
{
    cg::grid_group grid = cg::this_grid();
    const int tid = threadIdx.x;
    const long stride = (long)gridDim.x * 256;
    __shared__ int sh[256];

    // ---- P0: prep jobs (grid-stride) ----
    for (long idx = (long)blockIdx.x * 256 + tid; idx < JTOT; idx += stride)
        prep_job(a, idx);
    grid.sync();

    // ---- P1: count_hist ----
    if (tid < N_GRAPH) sh[tid] = 0;
    __syncthreads();
    for (long b = (long)blockIdx.x * 256 + tid; b < N_EDGES; b += stride)
        atomicAdd(&a.deg[a.ei[N_EDGES + b]], 1);
    for (long b = (long)blockIdx.x * 256 + tid; b < N_NODES; b += stride)
        atomicAdd(&sh[a.batch[b]], 1);
    __syncthreads();
    if (tid < N_GRAPH && sh[tid] > 0) atomicAdd(&a.gcnt[tid], sh[tid]);
    grid.sync();

    // ---- P2: per-chunk exclusive scan of deg (blocks 0..NBC-1) ----
    if (blockIdx.x < NBC) {
        int i = blockIdx.x * 256 + tid;
        int v = (i < N_NODES) ? a.deg[i] : 0;
        sh[tid] = v;
        __syncthreads();
        for (int off = 1; off < 256; off <<= 1) {
            int t = (tid >= off) ? sh[tid - off] : 0;
            __syncthreads();
            sh[tid] += t;
            __syncthreads();
        }
        if (i < N_NODES) a.rowstart[i] = sh[tid] - v;
        if (tid == 255) a.partial[blockIdx.x] = sh[255];
    }
    grid.sync();

    // ---- P3: scan partials (redundant per block) + add prefix ----
    if (blockIdx.x < NBC) {
        sh[tid] = (tid < NBC) ? a.partial[tid] : 0;
        __syncthreads();
        for (int off = 1; off < 256; off <<= 1) {
            int t = (tid >= off) ? sh[tid - off] : 0;
            __syncthreads();
            sh[tid] += t;
            __syncthreads();
        }
        int add = (blockIdx.x == 0) ? 0 : sh[blockIdx.x - 1];
        int i = blockIdx.x * 256 + tid;
        if (i < N_NODES) {
            int v = a.rowstart[i] + add;
            a.rowstart[i] = v;
            a.cursor[i] = v;
        }
        if (i == 0) a.rowstart[N_NODES] = N_EDGES;
    }
    grid.sync();

    // ---- P4: fill (scatter 8B records) ----
    for (long e = (long)blockIdx.x * 256 + tid; e < N_EDGES; e += stride) {
        int dst = a.ei[N_EDGES + e];
        int pos = atomicAdd(&a.cursor[dst], 1);
        a.csr2[pos] = make_int2(a.ei[e], (int)e);
    }
    grid.sync();

    // ---- P5: aec (coalesced per-position) ----
    for (long pos = (long)blockIdx.x * 256 + tid; pos < N_EDGES; pos += stride) {
        int2 se = a.csr2[pos];
        a.csr[pos] = se.x;
        const float* eap = a.ea + (long)se.y * 5;
        float e0 = eap[0], e1 = eap[1], e2 = eap[2], e3 = eap[3], e4 = eap[4];
#pragma unroll
        for (int l = 0; l < 2; l++) {
            const float* Me = a.MeAll + l * 40;
            f16x8 v;
#pragma unroll
            for (int hh = 0; hh < 8; hh++) {
                float s = e0 * Me[hh] + e1 * Me[8 + hh] + e2 * Me[16 + hh]
                        + e3 * Me[24 + hh] + e4 * Me[32 + hh];
                v[hh] = (_Float16)s;
            }
            *(f16x8*)(a.aec + (long)l * N_EDGES * 8 + pos * 8) = v;
        }
        const float* Me2 = a.MeAll + 80;
        float s2 = e0 * Me2[0] + e1 * Me2[1] + e2 * Me2[2] + e3 * Me2[3] + e4 * Me2[4];
        f16x8 v2;
#pragma unroll
        for (int hh = 0; hh < 8; hh++) v2[hh] = (_Float16)s2;
        *(f16x8*)(a.aec + (long)2 * N_EDGES * 8 + pos * 8) = v2;
    }
}

// ========== fused GAT aggregation (EXACT R19 structure) ====================
__global__ __launch_bounds__(256) void gat_agg_kernel(
    const int* __restrict__ rowstart, const int* __restrict__ csr,
    const _Float16* __restrict__ aec, const float* __restrict__ asb,
    const float* __restrict__ adb,
    const _Float16* __restrict__ h, const float* __restrict__ bias,
    _Float16* __restrict__ Oh, int H, int clog2)
{
    int node = blockIdx.x * 4 + (threadIdx.x >> 6);
    if (node >= N_NODES) return;
    const int lane = threadIdx.x & 63;
    const int half = lane >> 5;        // which edge of the pair
    const int c8   = (lane & 31) * 8;  // this lane's 8-channel group
    const int hc   = c8 >> clog2;      // head owning the group
    const int heff = lane & (H - 1);   // head for alpha compute
    const int grp  = lane >> 3;        // edge slot 0..7 in phase 1

    const float adn = adb[node * 8 + heff];
    const int beg = rowstart[node], end = rowstart[node + 1];

    float acc[8] = {};
    float den = 0.f;

    for (int i = beg; i < end; i += 8) {
        int idx = i + grp;
        const bool valid = (idx < end);
        if (!valid) idx = end - 1;
        const int sj = csr[idx];
        const float ae = (float)aec[(long)idx * 8 + heff];
        float al = asb[sj * 8 + heff] + adn + ae;
        al = fmaxf(al, 0.2f * al);
        const float pv = valid ? __expf(al) : 0.f;
#pragma unroll
        for (int jj = 0; jj < 4; jj++) {
            const int j = jj * 2 + half;
            const float pj = __shfl(pv, j * 8 + hc);
            const int srcj = __shfl(sj, j * 8);
            const int4 hw = *(const int4*)(h + (long)srcj * NHC + c8);
            den += pj;
            fma_mix_lo(acc[0], pj, hw.x); fma_mix_hi(acc[1], pj, hw.x);
            fma_mix_lo(acc[2], pj, hw.y); fma_mix_hi(acc[3], pj, hw.y);
            fma_mix_lo(acc[4], pj, hw.z); fma_mix_hi(acc[5], pj, hw.z);
            fma_mix_lo(acc[6], pj, hw.w); fma_mix_hi(acc[7], pj, hw.w);
        }
    }

    den += __shfl_xor(den, 32);
#pragma unroll
    for (int k = 0; k < 8; k++)
        acc[k] += __shfl_xor(acc[k], 32);

    if (half == 0) {
        const float w = 1.0f / (den + 1e-16f);
        const float4 b0 = *(const float4*)(bias + c8);
        const float4 b1 = *(const float4*)(bias + c8 + 4);
        const float bb[8] = {b0.x, b0.y, b0.z, b0.w, b1.x, b1.y, b1.z, b1.w};
        f16x8 oh;
#pragma unroll
        for (int k = 0; k < 8; k++) {
            float v = acc[k] * w + bb[k];
            v = (v > 0.f) ? v : (__expf(v) - 1.f);   // ELU; fp16 store masks fast-exp err
            oh[k] = (_Float16)v;
        }
        *(f16x8*)(Oh + (long)node * NHC + c8) = oh;
    }
}

// ================= final: out[g,:] = (pooled[g,:]@fcW2)/cnt + fcb2 =================
__global__ void final_kernel(const float* __restrict__ pooled, const int* __restrict__ gcnt,
                             const float* __restrict__ fcW2, const float* __restrict__ fcb2,
                             float* __restrict__ out)
{
    int g = blockIdx.x;
    int j = threadIdx.x;
    if (j >= DOUT) return;
    float s = 0.f;
    for (int k = 0; k < NHC; k++) s += pooled[g * NHC + k] * fcW2[k * DOUT + j];
    int c = gcnt[g];
    out[g * DOUT + j] = (c > 0) ? (s / (float)c + fcb2[j]) : 0.f;
}

extern "C" void kernel_launch(void* const* d_in, const int* in_sizes, int n_in,
                              void* d_out, int out_size, void* d_ws, size_t ws_size,
                              hipStream_t stream)
{
    const float* x    = (const float*)d_in[0];
    const int*   ei   = (const int*)  d_in[1];
    const float* ea   = (const float*)d_in[2];
    const int*   bat  = (const int*)  d_in[3];
    const float* W[3]   = {(const float*)d_in[4],  (const float*)d_in[10], (const float*)d_in[16]};
    const float* Asl[3] = {(const float*)d_in[5],  (const float*)d_in[11], (const float*)d_in[17]};
    const float* Adl[3] = {(const float*)d_in[6],  (const float*)d_in[12], (const float*)d_in[18]};
    const float* Wel[3] = {(const float*)d_in[7],  (const float*)d_in[13], (const float*)d_in[19]};
    const float* Ael[3] = {(const float*)d_in[8],  (const float*)d_in[14], (const float*)d_in[20]};
    const float* Bil[3] = {(const float*)d_in[9],  (const float*)d_in[15], (const float*)d_in[21]};
    const float* fcW1 = (const float*)d_in[22];
    const float* fcb1 = (const float*)d_in[23];
    const float* fcW2 = (const float*)d_in[24];
    const float* fcb2 = (const float*)d_in[25];

    // ---- workspace carve (bytes) ----
    char* w = (char*)d_ws;
    _Float16* h    = (_Float16*)w;     w += (size_t)N_NODES * NHC * 2;   // fp16 h
    _Float16* xh   = (_Float16*)w;     w += (size_t)N_NODES * DIN * 2;
    _Float16* xbh  = (_Float16*)w;     w += (size_t)N_NODES * NHC * 2;
    float*    asb  = (float*)w;        w += (size_t)N_NODES * 8 * 4;
    float*    adb  = (float*)w;        w += (size_t)N_NODES * 8 * 4;
    float*    asb3 = (float*)w;        w += (size_t)N_NODES * 8 * 4;
    float*    adb3 = (float*)w;        w += (size_t)N_NODES * 8 * 4;
    float*    MeAll= (float*)w;        w += 120 * 4;
    float*    pooled=(float*)w;        w += (size_t)N_GRAPH * NHC * 4;
    _Float16* W1th = (_Float16*)w;     w += (size_t)NHC * DIN * 2;
    _Float16* W2th = (_Float16*)w;     w += (size_t)NHC * NHC * 2;
    _Float16* W3th = (_Float16*)w;     w += (size_t)NHC * NHC * 2;
    _Float16* F1th = (_Float16*)w;     w += (size_t)NHC * NHC * 2;
    int* gcnt     = (int*)w;           w += N_GRAPH * 4;
    int* deg      = (int*)w;           w += (size_t)N_NODES * 4;
    int* rowstart = (int*)w;           w += (size_t)(N_NODES + 1) * 4;
    int* cursor   = (int*)w;           w += (size_t)N_NODES * 4;
    int* partial  = (int*)w;           w += 256 * 4;
    w = (char*)(((size_t)w + 15) & ~(size_t)15);
    int2* csr2    = (int2*)w;          w += (size_t)N_EDGES * 8;
    int* csr      = (int*)w;           w += (size_t)N_EDGES * 4;
    w = (char*)(((size_t)w + 15) & ~(size_t)15);
    _Float16* aec = (_Float16*)w;      w += (size_t)3 * N_EDGES * 8 * 2;  // 19.2 MB

    const int NB = (N_NODES + 255) / 256;

    BuildArgs ba;
    ba.x = x;
    ba.W1 = W[0]; ba.W2 = W[1]; ba.W3 = W[2]; ba.F1 = fcW1;
    ba.We1 = Wel[0]; ba.ae1 = Ael[0];
    ba.We2 = Wel[1]; ba.ae2 = Ael[1];
    ba.We3 = Wel[2]; ba.ae3 = Ael[2];
    ba.ei = ei; ba.batch = bat; ba.ea = ea;
    ba.xh = xh;
    ba.W1th = W1th; ba.W2th = W2th; ba.W3th = W3th; ba.F1th = F1th;
    ba.pooled = pooled; ba.deg = deg; ba.gcnt = gcnt; ba.MeAll = MeAll;
    ba.rowstart = rowstart; ba.cursor = cursor; ba.partial = partial;
    ba.csr2 = csr2; ba.csr = csr; ba.aec = aec;

    void* kp[] = { (void*)&ba };
    hipLaunchCooperativeKernel((const void*)build_kernel,
                               dim3(1024), dim3(256), kp, 0, stream);

    const int Hs[3] = {8, 8, 1};
    const int CL[3] = {5, 5, 8};
    const int Ks[3] = {DIN, NHC, NHC};

    const dim3 ggrid(4, 392);

    const _Float16* curh = xh;
    const _Float16* Wth[3] = {W1th, W2th, W3th};
    for (int l = 0; l < 3; l++) {
        const int H = Hs[l];
        const bool h1 = (l == 2);
        mfma_gemm_kernel<<<ggrid, 256, 0, stream>>>(
            curh, Wth[l], nullptr, h,
            Asl[l], Adl[l], h1 ? asb3 : asb, h1 ? adb3 : adb,
            nullptr, nullptr,
            N_NODES, Ks[l], 0);
        if (h1)
            sum8_kernel<<<NB, 256, 0, stream>>>(asb3, adb3, N_NODES);
        gat_agg_kernel<<<(N_NODES + 3) / 4, 256, 0, stream>>>(
            rowstart, csr, aec + (size_t)l * N_EDGES * 8,
            h1 ? asb3 : asb, h1 ? adb3 : adb, h, Bil[l], xbh, H, CL[l]);
        curh = xbh;
    }

    // fc1 + fused gelu + per-graph pooling (fc2 commutes with pooling)
    mfma_gemm_kernel<<<ggrid, 256, 0, stream>>>(
        xbh, F1th, fcb1, nullptr,
        nullptr, nullptr, nullptr, nullptr,
        bat, pooled,
        N_NODES, NHC, 3);
    final_kernel<<<N_GRAPH, 64, 0, stream>>>(pooled, gcnt, fcW2, fcb2, (float*)d_out);
}